// Round 8
// baseline (618.227 us; speedup 1.0000x reference)
//
#include <hip/hip_runtime.h>
#include <math.h>

// Problem constants
#define TB 2
#define TT 31
#define TH 160
#define TW 160
#define THW (TH*TW)            // 25600
#define NPER (TB*TT*THW)       // 1,587,200
#define HCN 16
#define TCH 8                  // t-chunk for k4

// Workspace layout (bytes). gates bf16: z-half [0,50.79MB), f-half [50.79,101.58MB).
// After k3, z-half is overwritten in-place with h (bf16). c2/c3 fp32 alias the
// (dead) f-half. Stats at the end. Total ~101.6MB.
#define GF_OFF_US  25395200L    // ushort offset of f-gates (2*16*31*25600)
#define C2_BYTE    50790400L    // byte offset of c2 (aliases f-gates, dead by then)
#define STATS_BYTE 101580800L

__device__ __forceinline__ float sigmoidf_(float x) {
    return __builtin_amdgcn_rcpf(1.f + __expf(-x));
}
__device__ __forceinline__ float tanhf_(float x) {
    return 2.f * __builtin_amdgcn_rcpf(1.f + __expf(-2.f * x)) - 1.f;
}
__device__ __forceinline__ unsigned short f2bf(float v) {
    unsigned int b = __float_as_uint(v);
    unsigned int r = (b + 0x7FFFu + ((b >> 16) & 1u)) >> 16;   // RNE
    return (unsigned short)r;
}
__device__ __forceinline__ float b2f(unsigned short u) {
    return __uint_as_float(((unsigned int)u) << 16);
}

// ---------- kernel 1: conv1 (all taps from LDS, no mid-loop barriers),
//            per-channel sum/sumsq + bf16 gate store ----------
// grid: (8 = chalf*4 + tchunk, 100 tiles, 2 b), block 256 = 32x8 tile
#define LSK 40
__global__ __launch_bounds__(256)
void k1_gates_stats(const float* __restrict__ in, const float* __restrict__ wg,
                    unsigned short* __restrict__ gout, float* __restrict__ stats) {
    __shared__ float pl[10*10*LSK];          // 10 t-planes, 10 rows x 40 (34 used)
    __shared__ float redS[4][16], redQ[4][16];

    int bx = blockIdx.x;
    int tc = bx & 3, chalf = bx >> 2;
    int tile = blockIdx.y, b = blockIdx.z;
    int ty0 = (tile / 5) * 8, tx0 = (tile % 5) * 32;
    int tid = threadIdx.x;
    int lyk = tid >> 5, lxk = tid & 31;
    int t0 = tc * 8;

    // stage 10 halo planes (t0-1 .. t0+8), 10x34 each, zero-padded
    for (int i = tid; i < 3400; i += 256) {
        int j = i / 340, pos = i - j*340;
        int py = pos / 34, px = pos - py*34;
        int t = t0 - 1 + j;
        int gy = ty0 - 1 + py, gx = tx0 - 1 + px;
        float v = 0.f;
        if (t >= 0 && t < TT && gy >= 0 && gy < TH && gx >= 0 && gx < TW)
            v = in[((long)(b*TT + t))*THW + gy*TW + gx];
        pl[j*(10*LSK) + py*LSK + px] = v;
    }
    __syncthreads();

    int c0 = chalf * 16;
    long gbase = chalf ? GF_OFF_US : 0L;
    int y = ty0 + lyk, x = tx0 + lxk;
    int hw = y*TW + x;

    float s[16], q[16];
    #pragma unroll
    for (int c = 0; c < 16; ++c) { s[c] = 0.f; q[c] = 0.f; }

    for (int j = 1; j <= 8; ++j) {
        int t = t0 - 1 + j;
        if (t >= TT) break;                  // uniform
        float tap[27];
        #pragma unroll
        for (int kt = 0; kt < 3; ++kt)
            #pragma unroll
            for (int ky = 0; ky < 3; ++ky)
                #pragma unroll
                for (int kx = 0; kx < 3; ++kx)
                    tap[kt*9 + ky*3 + kx] =
                        pl[(j-1+kt)*(10*LSK) + (lyk+ky)*LSK + (lxk+kx)];
        #pragma unroll
        for (int c = 0; c < 16; ++c) {
            const float* w = wg + (c0 + c)*27;
            float v = 0.f;
            #pragma unroll
            for (int i = 0; i < 27; ++i) v = fmaf(w[i], tap[i], v);
            s[c] += v; q[c] += v*v;
            gout[gbase + ((long)((b*HCN + c)*TT + t))*THW + hw] = f2bf(v);
        }
    }

    // block reduce 16 channels x (sum, sumsq)
    int lane = tid & 63, wid = tid >> 6;
    #pragma unroll
    for (int c = 0; c < 16; ++c) {
        float ss = s[c], qq = q[c];
        #pragma unroll
        for (int off = 32; off > 0; off >>= 1) {
            ss += __shfl_down(ss, off, 64);
            qq += __shfl_down(qq, off, 64);
        }
        if (lane == 0) { redS[wid][c] = ss; redQ[wid][c] = qq; }
    }
    __syncthreads();
    if (tid < 16) {
        int ch = c0 + tid;
        float ss = redS[0][tid] + redS[1][tid] + redS[2][tid] + redS[3][tid];
        float qq = redQ[0][tid] + redQ[1][tid] + redQ[2][tid] + redQ[3][tid];
        atomicAdd(&stats[ch], ss);
        atomicAdd(&stats[32 + ch], qq);
    }
}

// ---------- kernel 2: finalize gate BN params ----------
__global__ void k2_fin1(const float* __restrict__ stats, const float* __restrict__ gamma,
                        const float* __restrict__ beta, float* __restrict__ ab) {
    int c = threadIdx.x;
    if (c < 32) {
        float n = (float)NPER;
        float mean = stats[c] / n;
        float var  = stats[32 + c] / n - mean*mean;
        float a = gamma[c] * rsqrtf(var + 1e-5f);
        ab[c]      = a;
        ab[32 + c] = beta[c] - mean * a;
    }
}

// ---------- kernel 3: pointwise BN + act + scan (bf16 in, bf16 h in-place) ----------
// grid: (25, 16 ch, 2 b), block 256; each thread: 4 consecutive hw elems, scans t
__global__ __launch_bounds__(256)
void k3_scan(unsigned short* __restrict__ g, const float* __restrict__ ab,
             const int* __restrict__ rev_p) {
    int c = blockIdx.y, b = blockIdx.z;
    int p4 = blockIdx.x * blockDim.x + threadIdx.x;    // ushort4 index in plane
    float az = ab[c],      bz = ab[32 + c];
    float af = ab[16 + c], bf = ab[48 + c];
    int rev = rev_p[0];

    ushort4* g4 = (ushort4*)g;
    long zb = ((long)((b*HCN + c)*TT)) * (THW/4) + p4;
    long fb = zb + GF_OFF_US/4;

    float h0 = 0.f, h1 = 0.f, h2 = 0.f, h3 = 0.f;

#define K3_STEP(t)                                                        \
    {                                                                     \
        long o = (long)(t) * (THW/4);                                     \
        ushort4 zu = g4[zb + o];                                          \
        ushort4 fu = g4[fb + o];                                          \
        float z0 = tanhf_(fmaf(az, b2f(zu.x), bz));                       \
        float z1 = tanhf_(fmaf(az, b2f(zu.y), bz));                       \
        float z2 = tanhf_(fmaf(az, b2f(zu.z), bz));                       \
        float z3 = tanhf_(fmaf(az, b2f(zu.w), bz));                       \
        float f0 = sigmoidf_(fmaf(af, b2f(fu.x), bf));                    \
        float f1 = sigmoidf_(fmaf(af, b2f(fu.y), bf));                    \
        float f2 = sigmoidf_(fmaf(af, b2f(fu.z), bf));                    \
        float f3 = sigmoidf_(fmaf(af, b2f(fu.w), bf));                    \
        h0 = f0*h0 + (1.f - f0)*z0;                                       \
        h1 = f1*h1 + (1.f - f1)*z1;                                       \
        h2 = f2*h2 + (1.f - f2)*z2;                                       \
        h3 = f3*h3 + (1.f - f3)*z3;                                       \
        ushort4 hu;                                                       \
        hu.x = f2bf(h0); hu.y = f2bf(h1); hu.z = f2bf(h2); hu.w = f2bf(h3); \
        g4[zb + o] = hu;                                                  \
    }

    if (!rev) {
        for (int t = 0; t < TT; ++t) K3_STEP(t)
    } else {
        for (int t = TT - 1; t >= 0; --t) K3_STEP(t)
    }
#undef K3_STEP
}

// ---------- kernel 4: conv2+conv3 over bf16 h.
// Stage-all-then-sweep: 2 t-sub-phases per block, all 16 ch staged in LDS (bf16),
// ONE barrier per phase, sweep entirely from LDS (no vmcnt drains in inner loop).
// Each thread computes 2 adjacent x outputs -> taps read as ds_read2_b32 pairs.
// grid: (100 tiles 32x8, 4 t-chunks, 2 b), block 128 (16 x-pairs x 8 rows)
__global__ __launch_bounds__(128)
void k4_conv23(const unsigned short* __restrict__ hb, const float* __restrict__ wsc,
               const float* __restrict__ wsh, float* __restrict__ c2,
               float* __restrict__ c3, float* __restrict__ stats2) {
    __shared__ unsigned int pl[16*6*200];   // 16 ch-slots x 6 t-planes x (10 rows x 20 uints)
    __shared__ float red[2][4];

    int b  = blockIdx.z;
    int t0 = blockIdx.y * TCH;
    int t1 = min(t0 + TCH - 1, TT - 1);
    int tile = blockIdx.x;
    int ty0 = (tile / 5) * 8, tx0 = (tile % 5) * 32;
    int tid = threadIdx.x;
    int k   = tid & 15;          // x-pair index
    int lyk = tid >> 4;          // row 0..7
    int y = ty0 + lyk, x0 = tx0 + 2*k;

    unsigned short* plu16 = (unsigned short*)pl;

    float s2l = 0.f, q2l = 0.f, s3l = 0.f, q3l = 0.f;

    #pragma unroll 1
    for (int ph = 0; ph < 2; ++ph) {
        int ts  = ph ? (t0 + 3)            : max(t0 - 1, 0);
        int te  = ph ? min(t0 + 8, TT - 1) : min(t0 + 4, TT - 1);
        int olo = ph ? (t0 + 4)            : t0;
        int ohi = ph ? t1                  : min(t0 + 3, t1);
        int nt = te - ts + 1;               // <= 6
        int n340 = nt * 340;

        __syncthreads();   // previous sweep done reading LDS
        // stage 16 ch x nt planes x 10x34 (bf16)
        for (int s = 0; s < 16; ++s) {
            long cb = ((long)((b*HCN + s)*TT + ts)) * THW;
            unsigned short* pls = plu16 + (s*6)*400;
            #pragma unroll 4
            for (int i2 = tid; i2 < n340; i2 += 128) {
                int j = i2 / 340;
                int pos = i2 - j*340;
                int py = pos / 34;
                int px = pos - py*34;
                int gy = ty0 - 1 + py, gx = tx0 - 1 + px;
                bool ok = (gy >= 0 && gy < TH && gx >= 0 && gx < TW);
                unsigned short v = ok ? hb[cb + (long)j*THW + gy*TW + gx] : (unsigned short)0;
                pls[j*400 + py*40 + px] = v;
            }
        }
        __syncthreads();

        // rolling accumulators, 2 outputs (x0, x0+1) each
        float aP2x=0.f,aP2y=0.f,aC2x=0.f,aC2y=0.f,aN2x=0.f,aN2y=0.f;
        float aP3x=0.f,aP3y=0.f,aC3x=0.f,aC3y=0.f,aN3x=0.f,aN3y=0.f;

        for (int t_in = ts; t_in <= te; ++t_in) {
            int j = t_in - ts;
            #pragma unroll
            for (int cc = 0; cc < 8; ++cc) {
                const float* w2 = wsc + cc*27;
                const float* w3 = wsh + cc*27;
                #pragma unroll
                for (int ky = 0; ky < 3; ++ky) {
                    // conv2 taps from slot cc
                    {
                        int ub = ((cc*6 + j)*10 + (lyk + ky))*20 + k;
                        unsigned int u0 = pl[ub], u1 = pl[ub + 1];
                        float v0 = __uint_as_float(u0 << 16);
                        float v1 = __uint_as_float(u0 & 0xffff0000u);
                        float v2 = __uint_as_float(u1 << 16);
                        float v3 = __uint_as_float(u1 & 0xffff0000u);
                        float wN0 = w2[ky*3+0],   wN1 = w2[ky*3+1],   wN2 = w2[ky*3+2];
                        float wC0 = w2[9+ky*3+0], wC1 = w2[9+ky*3+1], wC2 = w2[9+ky*3+2];
                        float wP0 = w2[18+ky*3+0],wP1 = w2[18+ky*3+1],wP2 = w2[18+ky*3+2];
                        aN2x = fmaf(wN0,v0,aN2x); aN2x = fmaf(wN1,v1,aN2x); aN2x = fmaf(wN2,v2,aN2x);
                        aN2y = fmaf(wN0,v1,aN2y); aN2y = fmaf(wN1,v2,aN2y); aN2y = fmaf(wN2,v3,aN2y);
                        aC2x = fmaf(wC0,v0,aC2x); aC2x = fmaf(wC1,v1,aC2x); aC2x = fmaf(wC2,v2,aC2x);
                        aC2y = fmaf(wC0,v1,aC2y); aC2y = fmaf(wC1,v2,aC2y); aC2y = fmaf(wC2,v3,aC2y);
                        aP2x = fmaf(wP0,v0,aP2x); aP2x = fmaf(wP1,v1,aP2x); aP2x = fmaf(wP2,v2,aP2x);
                        aP2y = fmaf(wP0,v1,aP2y); aP2y = fmaf(wP1,v2,aP2y); aP2y = fmaf(wP2,v3,aP2y);
                    }
                    // conv3 taps from slot 8+cc
                    {
                        int ub = (((8+cc)*6 + j)*10 + (lyk + ky))*20 + k;
                        unsigned int u0 = pl[ub], u1 = pl[ub + 1];
                        float v0 = __uint_as_float(u0 << 16);
                        float v1 = __uint_as_float(u0 & 0xffff0000u);
                        float v2 = __uint_as_float(u1 << 16);
                        float v3 = __uint_as_float(u1 & 0xffff0000u);
                        float wN0 = w3[ky*3+0],   wN1 = w3[ky*3+1],   wN2 = w3[ky*3+2];
                        float wC0 = w3[9+ky*3+0], wC1 = w3[9+ky*3+1], wC2 = w3[9+ky*3+2];
                        float wP0 = w3[18+ky*3+0],wP1 = w3[18+ky*3+1],wP2 = w3[18+ky*3+2];
                        aN3x = fmaf(wN0,v0,aN3x); aN3x = fmaf(wN1,v1,aN3x); aN3x = fmaf(wN2,v2,aN3x);
                        aN3y = fmaf(wN0,v1,aN3y); aN3y = fmaf(wN1,v2,aN3y); aN3y = fmaf(wN2,v3,aN3y);
                        aC3x = fmaf(wC0,v0,aC3x); aC3x = fmaf(wC1,v1,aC3x); aC3x = fmaf(wC2,v2,aC3x);
                        aC3y = fmaf(wC0,v1,aC3y); aC3y = fmaf(wC1,v2,aC3y); aC3y = fmaf(wC2,v3,aC3y);
                        aP3x = fmaf(wP0,v0,aP3x); aP3x = fmaf(wP1,v1,aP3x); aP3x = fmaf(wP2,v2,aP3x);
                        aP3y = fmaf(wP0,v1,aP3y); aP3y = fmaf(wP1,v2,aP3y); aP3y = fmaf(wP2,v3,aP3y);
                    }
                }
            }
            int t_out = t_in - 1;
            if (t_out >= olo && t_out <= ohi) {
                long oidx = ((long)(b*TT + t_out)) * THW + (long)y*TW + x0;
                *(float2*)&c2[oidx] = make_float2(aP2x, aP2y);
                *(float2*)&c3[oidx] = make_float2(aP3x, aP3y);
                s2l += aP2x + aP2y; q2l += aP2x*aP2x + aP2y*aP2y;
                s3l += aP3x + aP3y; q3l += aP3x*aP3x + aP3y*aP3y;
            }
            aP2x=aC2x; aC2x=aN2x; aN2x=0.f;  aP2y=aC2y; aC2y=aN2y; aN2y=0.f;
            aP3x=aC3x; aC3x=aN3x; aN3x=0.f;  aP3y=aC3y; aC3y=aN3y; aN3y=0.f;
        }
        if (ohi == te) {    // t_out = te completes after last plane (zero pad beyond)
            long oidx = ((long)(b*TT + te)) * THW + (long)y*TW + x0;
            *(float2*)&c2[oidx] = make_float2(aP2x, aP2y);
            *(float2*)&c3[oidx] = make_float2(aP3x, aP3y);
            s2l += aP2x + aP2y; q2l += aP2x*aP2x + aP2y*aP2y;
            s3l += aP3x + aP3y; q3l += aP3x*aP3x + aP3y*aP3y;
        }
    }

    #pragma unroll
    for (int off = 32; off > 0; off >>= 1) {
        s2l += __shfl_down(s2l, off, 64);
        q2l += __shfl_down(q2l, off, 64);
        s3l += __shfl_down(s3l, off, 64);
        q3l += __shfl_down(q3l, off, 64);
    }
    int lane = tid & 63, wid = tid >> 6;
    __syncthreads();
    if (lane == 0) { red[wid][0] = s2l; red[wid][1] = q2l; red[wid][2] = s3l; red[wid][3] = q3l; }
    __syncthreads();
    if (tid == 0) {
        atomicAdd(&stats2[0], red[0][0] + red[1][0]);
        atomicAdd(&stats2[1], red[0][1] + red[1][1]);
        atomicAdd(&stats2[2], red[0][2] + red[1][2]);
        atomicAdd(&stats2[3], red[0][3] + red[1][3]);
    }
}

// ---------- kernel 5: finalize scale/shift BN params ----------
__global__ void k5_fin2(const float* __restrict__ stats2,
                        const float* __restrict__ gs, const float* __restrict__ bs,
                        const float* __restrict__ gt, const float* __restrict__ bt,
                        float* __restrict__ ab2) {
    if (threadIdx.x == 0) {
        float n = (float)NPER;
        float m2 = stats2[0] / n, v2 = stats2[1] / n - m2*m2;
        float a2 = gs[0] * rsqrtf(v2 + 1e-5f);
        ab2[0] = a2; ab2[1] = bs[0] - m2*a2;
        float m3 = stats2[2] / n, v3 = stats2[3] / n - m3*m3;
        float a3 = gt[0] * rsqrtf(v3 + 1e-5f);
        ab2[2] = a3; ab2[3] = bt[0] - m3*a3;
    }
}

// ---------- kernel 6: epilogue, float4 ----------
__global__ __launch_bounds__(256)
void k6_final(const float4* __restrict__ c2, const float4* __restrict__ c3,
              const float* __restrict__ ab2, float4* __restrict__ out) {
    int i = blockIdx.x * blockDim.x + threadIdx.x;
    if (i < NPER/4) {
        float a2 = ab2[0], b2 = ab2[1], a3 = ab2[2], b3 = ab2[3];
        float4 v2 = c2[i], v3 = c3[i];
        float4 sc, sh;
        sc.x = sigmoidf_(fmaf(a2, v2.x, b2) + 2.f) + 1e-4f;
        sc.y = sigmoidf_(fmaf(a2, v2.y, b2) + 2.f) + 1e-4f;
        sc.z = sigmoidf_(fmaf(a2, v2.z, b2) + 2.f) + 1e-4f;
        sc.w = sigmoidf_(fmaf(a2, v2.w, b2) + 2.f) + 1e-4f;
        sh.x = fmaf(a3, v3.x, b3);
        sh.y = fmaf(a3, v3.y, b3);
        sh.z = fmaf(a3, v3.z, b3);
        sh.w = fmaf(a3, v3.w, b3);
        out[i] = sc;
        out[NPER/4 + i] = sh;
    }
}

// ---------- launch ----------
extern "C" void kernel_launch(void* const* d_in, const int* in_sizes, int n_in,
                              void* d_out, int out_size, void* d_ws, size_t ws_size,
                              hipStream_t stream) {
    const float* in          = (const float*)d_in[0];
    const float* w_gate      = (const float*)d_in[1];
    const float* gamma_gate  = (const float*)d_in[2];
    const float* beta_gate   = (const float*)d_in[3];
    const float* w_scale     = (const float*)d_in[4];
    const float* gamma_scale = (const float*)d_in[5];
    const float* beta_scale  = (const float*)d_in[6];
    const float* w_shift     = (const float*)d_in[7];
    const float* gamma_shift = (const float*)d_in[8];
    const float* beta_shift  = (const float*)d_in[9];
    const int*   rev         = (const int*)d_in[10];

    unsigned short* g   = (unsigned short*)d_ws;                    // gates bf16 (z then f); z-half becomes h
    float* c2  = (float*)((char*)d_ws + C2_BYTE);                   // aliases dead f-gates
    float* c3  = c2 + NPER;
    float* st  = (float*)((char*)d_ws + STATS_BYTE);
    float* s1  = st;            // 64
    float* ab1 = st + 64;       // 64
    float* s2  = st + 128;      // 4
    float* ab2 = st + 132;      // 4
    float* out = (float*)d_out;

    hipMemsetAsync(st, 0, 136 * sizeof(float), stream);

    k1_gates_stats<<<dim3(8, 100, TB), 256, 0, stream>>>(in, w_gate, g, s1);
    k2_fin1<<<1, 32, 0, stream>>>(s1, gamma_gate, beta_gate, ab1);
    k3_scan<<<dim3(25, HCN, TB), 256, 0, stream>>>(g, ab1, rev);
    k4_conv23<<<dim3(100, 4, TB), 128, 0, stream>>>(g, w_scale, w_shift, c2, c3, s2);
    k5_fin2<<<1, 64, 0, stream>>>(s2, gamma_scale, beta_scale, gamma_shift, beta_shift, ab2);
    k6_final<<<(NPER/4 + 255)/256, 256, 0, stream>>>((const float4*)c2, (const float4*)c3, ab2, (float4*)out);
}

// Round 9
// 262.577 us; speedup vs baseline: 2.3545x; 2.3545x over previous
//
#include <hip/hip_runtime.h>
#include <math.h>

// Problem constants
#define TB 2
#define TT 31
#define TH 160
#define TW 160
#define THW (TH*TW)            // 25600
#define NPER (TB*TT*THW)       // 1,587,200
#define HCN 16
#define TCH 8                  // t-chunk for k4
#define LSK 40                 // LDS row stride (34 used) -> 2-way banking

// Workspace layout (bytes). gates bf16: z-half [0,50.79MB), f-half [50.79,101.58MB).
// After k3, z-half is overwritten in-place with h (bf16). c2/c3 fp32 alias the
// (dead) f-half. Stats at the end. Total ~101.6MB.
#define GF_OFF_US  25395200L    // ushort offset of f-gates (2*16*31*25600)
#define C2_BYTE    50790400L    // byte offset of c2 (aliases f-gates, dead by then)
#define STATS_BYTE 101580800L

__device__ __forceinline__ float sigmoidf_(float x) {
    return __builtin_amdgcn_rcpf(1.f + __expf(-x));
}
__device__ __forceinline__ float tanhf_(float x) {
    return 2.f * __builtin_amdgcn_rcpf(1.f + __expf(-2.f * x)) - 1.f;
}
__device__ __forceinline__ unsigned short f2bf(float v) {
    unsigned int b = __float_as_uint(v);
    unsigned int r = (b + 0x7FFFu + ((b >> 16) & 1u)) >> 16;   // RNE
    return (unsigned short)r;
}
__device__ __forceinline__ float b2f(unsigned short u) {
    return __uint_as_float(((unsigned int)u) << 16);
}

// ---------- kernel 1: conv1 (all taps from LDS, no mid-loop barriers),
//            per-channel sum/sumsq + bf16 gate store ----------
// grid: (8 = chalf*4 + tchunk, 100 tiles, 2 b), block 256 = 32x8 tile
__global__ __launch_bounds__(256)
void k1_gates_stats(const float* __restrict__ in, const float* __restrict__ wg,
                    unsigned short* __restrict__ gout, float* __restrict__ stats) {
    __shared__ float pl[10*10*LSK];          // 10 t-planes, 10 rows x 40 (34 used)
    __shared__ float redS[4][16], redQ[4][16];

    int bx = blockIdx.x;
    int tc = bx & 3, chalf = bx >> 2;
    int tile = blockIdx.y, b = blockIdx.z;
    int ty0 = (tile / 5) * 8, tx0 = (tile % 5) * 32;
    int tid = threadIdx.x;
    int lyk = tid >> 5, lxk = tid & 31;
    int t0 = tc * 8;

    // stage 10 halo planes (t0-1 .. t0+8), 10x34 each, zero-padded
    for (int i = tid; i < 3400; i += 256) {
        int j = i / 340, pos = i - j*340;
        int py = pos / 34, px = pos - py*34;
        int t = t0 - 1 + j;
        int gy = ty0 - 1 + py, gx = tx0 - 1 + px;
        float v = 0.f;
        if (t >= 0 && t < TT && gy >= 0 && gy < TH && gx >= 0 && gx < TW)
            v = in[((long)(b*TT + t))*THW + gy*TW + gx];
        pl[j*(10*LSK) + py*LSK + px] = v;
    }
    __syncthreads();

    int c0 = chalf * 16;
    long gbase = chalf ? GF_OFF_US : 0L;
    int y = ty0 + lyk, x = tx0 + lxk;
    int hw = y*TW + x;

    float s[16], q[16];
    #pragma unroll
    for (int c = 0; c < 16; ++c) { s[c] = 0.f; q[c] = 0.f; }

    for (int j = 1; j <= 8; ++j) {
        int t = t0 - 1 + j;
        if (t >= TT) break;                  // uniform
        float tap[27];
        #pragma unroll
        for (int kt = 0; kt < 3; ++kt)
            #pragma unroll
            for (int ky = 0; ky < 3; ++ky)
                #pragma unroll
                for (int kx = 0; kx < 3; ++kx)
                    tap[kt*9 + ky*3 + kx] =
                        pl[(j-1+kt)*(10*LSK) + (lyk+ky)*LSK + (lxk+kx)];
        #pragma unroll
        for (int c = 0; c < 16; ++c) {
            const float* w = wg + (c0 + c)*27;
            float v = 0.f;
            #pragma unroll
            for (int i = 0; i < 27; ++i) v = fmaf(w[i], tap[i], v);
            s[c] += v; q[c] += v*v;
            gout[gbase + ((long)((b*HCN + c)*TT + t))*THW + hw] = f2bf(v);
        }
    }

    // block reduce 16 channels x (sum, sumsq)
    int lane = tid & 63, wid = tid >> 6;
    #pragma unroll
    for (int c = 0; c < 16; ++c) {
        float ss = s[c], qq = q[c];
        #pragma unroll
        for (int off = 32; off > 0; off >>= 1) {
            ss += __shfl_down(ss, off, 64);
            qq += __shfl_down(qq, off, 64);
        }
        if (lane == 0) { redS[wid][c] = ss; redQ[wid][c] = qq; }
    }
    __syncthreads();
    if (tid < 16) {
        int ch = c0 + tid;
        float ss = redS[0][tid] + redS[1][tid] + redS[2][tid] + redS[3][tid];
        float qq = redQ[0][tid] + redQ[1][tid] + redQ[2][tid] + redQ[3][tid];
        atomicAdd(&stats[ch], ss);
        atomicAdd(&stats[32 + ch], qq);
    }
}

// ---------- kernel 2: finalize gate BN params ----------
__global__ void k2_fin1(const float* __restrict__ stats, const float* __restrict__ gamma,
                        const float* __restrict__ beta, float* __restrict__ ab) {
    int c = threadIdx.x;
    if (c < 32) {
        float n = (float)NPER;
        float mean = stats[c] / n;
        float var  = stats[32 + c] / n - mean*mean;
        float a = gamma[c] * rsqrtf(var + 1e-5f);
        ab[c]      = a;
        ab[32 + c] = beta[c] - mean * a;
    }
}

// ---------- kernel 3: pointwise BN + act + scan (bf16 in, bf16 h in-place) ----------
// grid: (25, 16 ch, 2 b), block 256; each thread: 4 consecutive hw elems, scans t
__global__ __launch_bounds__(256)
void k3_scan(unsigned short* __restrict__ g, const float* __restrict__ ab,
             const int* __restrict__ rev_p) {
    int c = blockIdx.y, b = blockIdx.z;
    int p4 = blockIdx.x * blockDim.x + threadIdx.x;    // ushort4 index in plane
    float az = ab[c],      bz = ab[32 + c];
    float af = ab[16 + c], bf = ab[48 + c];
    int rev = rev_p[0];

    ushort4* g4 = (ushort4*)g;
    long zb = ((long)((b*HCN + c)*TT)) * (THW/4) + p4;
    long fb = zb + GF_OFF_US/4;

    float h0 = 0.f, h1 = 0.f, h2 = 0.f, h3 = 0.f;

#define K3_STEP(t)                                                        \
    {                                                                     \
        long o = (long)(t) * (THW/4);                                     \
        ushort4 zu = g4[zb + o];                                          \
        ushort4 fu = g4[fb + o];                                          \
        float z0 = tanhf_(fmaf(az, b2f(zu.x), bz));                       \
        float z1 = tanhf_(fmaf(az, b2f(zu.y), bz));                       \
        float z2 = tanhf_(fmaf(az, b2f(zu.z), bz));                       \
        float z3 = tanhf_(fmaf(az, b2f(zu.w), bz));                       \
        float f0 = sigmoidf_(fmaf(af, b2f(fu.x), bf));                    \
        float f1 = sigmoidf_(fmaf(af, b2f(fu.y), bf));                    \
        float f2 = sigmoidf_(fmaf(af, b2f(fu.z), bf));                    \
        float f3 = sigmoidf_(fmaf(af, b2f(fu.w), bf));                    \
        h0 = f0*h0 + (1.f - f0)*z0;                                       \
        h1 = f1*h1 + (1.f - f1)*z1;                                       \
        h2 = f2*h2 + (1.f - f2)*z2;                                       \
        h3 = f3*h3 + (1.f - f3)*z3;                                       \
        ushort4 hu;                                                       \
        hu.x = f2bf(h0); hu.y = f2bf(h1); hu.z = f2bf(h2); hu.w = f2bf(h3); \
        g4[zb + o] = hu;                                                  \
    }

    if (!rev) {
        for (int t = 0; t < TT; ++t) K3_STEP(t)
    } else {
        for (int t = TT - 1; t >= 0; --t) K3_STEP(t)
    }
#undef K3_STEP
}

// ---------- kernel 4: conv2+conv3 over bf16 h.
// R5 skeleton (block 256, 32x8 tile, 4-load staging) but 4 planes per barrier:
// 20 barriers/block instead of 80 -> 4x fewer vmcnt(0) barrier drains.
// Double-buffered at GROUP level: LDS = 2 buf x 4 planes x 2 convs x 400 floats = 25.6 KB.
// grid: (100 tiles, 4 t-chunks, 2 b), block 256
__global__ __launch_bounds__(256)
void k4_conv23(const unsigned short* __restrict__ hb, const float* __restrict__ wsc,
               const float* __restrict__ wsh, float* __restrict__ c2,
               float* __restrict__ c3, float* __restrict__ stats2) {
    __shared__ float pl[2][4][2][10*LSK];   // [buf][plane-in-group][conv][10x40]
    __shared__ float red[4][4];

    int b  = blockIdx.z;
    int t0 = blockIdx.y * TCH;
    int t1 = min(t0 + TCH - 1, TT - 1);
    int tile = blockIdx.x;
    int ty0 = (tile / 5) * 8, tx0 = (tile % 5) * 32;
    int tid = threadIdx.x;
    int lyk = tid >> 5, lxk = tid & 31;
    int y = ty0 + lyk, x = tx0 + lxk;

    int ts = max(t0 - 1, 0), te = min(t1 + 1, TT - 1);
    int nplanes = (te - ts + 1) * 8;        // 64 / 72 / 80 — divisible by 4
    int ngroups = nplanes >> 2;

    int i1 = tid + 256;
    int py0 = tid / 34, px0 = tid - py0*34;
    int py1 = i1 / 34, px1 = i1 - py1*34;
    int gy0 = ty0 - 1 + py0, gx0 = tx0 - 1 + px0;
    int gy1 = ty0 - 1 + py1, gx1 = tx0 - 1 + px1;
    bool ok0 = (gy0 >= 0 && gy0 < TH && gx0 >= 0 && gx0 < TW);
    bool ok1 = (i1 < 340) && (gy1 >= 0 && gy1 < TH && gx1 >= 0 && gx1 < TW);
    long off0 = (long)gy0*TW + gx0, off1 = (long)gy1*TW + gx1;
    int l0 = py0*LSK + px0, l1 = py1*LSK + px1;

    float accP2 = 0.f, accC2 = 0.f, accN2 = 0.f;
    float accP3 = 0.f, accC3 = 0.f, accN3 = 0.f;
    float s2l = 0.f, q2l = 0.f, s3l = 0.f, q3l = 0.f;

    // prefetch group 0 (16 ushort regs)
    unsigned short r2a[4], r2b[4], r3a[4], r3b[4];
    #pragma unroll
    for (int j = 0; j < 4; ++j) {
        int c = j & 7, t_in = ts + (j >> 3);
        long b2o = ((long)((b*HCN + c)*TT + t_in)) * THW;
        long b3o = ((long)((b*HCN + 8 + c)*TT + t_in)) * THW;
        r2a[j] = ok0 ? hb[b2o + off0] : 0;
        r2b[j] = ok1 ? hb[b2o + off1] : 0;
        r3a[j] = ok0 ? hb[b3o + off0] : 0;
        r3b[j] = ok1 ? hb[b3o + off1] : 0;
    }

    for (int g = 0; g < ngroups; ++g) {
        int buf = g & 1;
        // stage current group from regs
        #pragma unroll
        for (int j = 0; j < 4; ++j) {
            pl[buf][j][0][l0] = b2f(r2a[j]);
            pl[buf][j][1][l0] = b2f(r3a[j]);
            if (i1 < 340) { pl[buf][j][0][l1] = b2f(r2b[j]); pl[buf][j][1][l1] = b2f(r3b[j]); }
        }
        // prefetch next group
        if (g + 1 < ngroups) {
            #pragma unroll
            for (int j = 0; j < 4; ++j) {
                int p = (g + 1)*4 + j;
                int c = p & 7, t_in = ts + (p >> 3);
                long b2o = ((long)((b*HCN + c)*TT + t_in)) * THW;
                long b3o = ((long)((b*HCN + 8 + c)*TT + t_in)) * THW;
                r2a[j] = ok0 ? hb[b2o + off0] : 0;
                r2b[j] = ok1 ? hb[b2o + off1] : 0;
                r3a[j] = ok0 ? hb[b3o + off0] : 0;
                r3b[j] = ok1 ? hb[b3o + off1] : 0;
            }
        }
        __syncthreads();   // publishes this group's LDS; prev group's reads are older in program order

        // compute 4 planes from LDS
        #pragma unroll
        for (int j = 0; j < 4; ++j) {
            int p = g*4 + j;
            int c = p & 7, t_in = ts + (p >> 3);
            float t2[9], t3[9];
            #pragma unroll
            for (int ky = 0; ky < 3; ++ky)
                #pragma unroll
                for (int kx = 0; kx < 3; ++kx) {
                    int li = (lyk + ky)*LSK + (lxk + kx);
                    t2[ky*3 + kx] = pl[buf][j][0][li];
                    t3[ky*3 + kx] = pl[buf][j][1][li];
                }
            const float* w2 = wsc + c*27;
            const float* w3 = wsh + c*27;
            #pragma unroll
            for (int i = 0; i < 9; ++i) {
                accN2 = fmaf(w2[i],      t2[i], accN2);
                accC2 = fmaf(w2[9 + i],  t2[i], accC2);
                accP2 = fmaf(w2[18 + i], t2[i], accP2);
                accN3 = fmaf(w3[i],      t3[i], accN3);
                accC3 = fmaf(w3[9 + i],  t3[i], accC3);
                accP3 = fmaf(w3[18 + i], t3[i], accP3);
            }

            if (c == 7) {
                int t_out = t_in - 1;
                if (t_out >= t0 && t_out <= t1) {
                    long oidx = ((long)(b*TT + t_out)) * THW + (long)y*TW + x;
                    c2[oidx] = accP2; c3[oidx] = accP3;
                    s2l += accP2; q2l += accP2*accP2;
                    s3l += accP3; q3l += accP3*accP3;
                }
                accP2 = accC2; accC2 = accN2; accN2 = 0.f;
                accP3 = accC3; accC3 = accN3; accN3 = 0.f;
            }
        }
    }
    if (t1 == TT - 1) {
        long oidx = ((long)(b*TT + (TT - 1))) * THW + (long)y*TW + x;
        c2[oidx] = accP2; c3[oidx] = accP3;
        s2l += accP2; q2l += accP2*accP2;
        s3l += accP3; q3l += accP3*accP3;
    }

    #pragma unroll
    for (int off = 32; off > 0; off >>= 1) {
        s2l += __shfl_down(s2l, off, 64);
        q2l += __shfl_down(q2l, off, 64);
        s3l += __shfl_down(s3l, off, 64);
        q3l += __shfl_down(q3l, off, 64);
    }
    int lane = tid & 63, wid = tid >> 6;
    __syncthreads();
    if (lane == 0) { red[0][wid] = s2l; red[1][wid] = q2l; red[2][wid] = s3l; red[3][wid] = q3l; }
    __syncthreads();
    if (tid == 0) {
        #pragma unroll
        for (int j = 0; j < 4; ++j)
            atomicAdd(&stats2[j], red[j][0] + red[j][1] + red[j][2] + red[j][3]);
    }
}

// ---------- kernel 5: finalize scale/shift BN params ----------
__global__ void k5_fin2(const float* __restrict__ stats2,
                        const float* __restrict__ gs, const float* __restrict__ bs,
                        const float* __restrict__ gt, const float* __restrict__ bt,
                        float* __restrict__ ab2) {
    if (threadIdx.x == 0) {
        float n = (float)NPER;
        float m2 = stats2[0] / n, v2 = stats2[1] / n - m2*m2;
        float a2 = gs[0] * rsqrtf(v2 + 1e-5f);
        ab2[0] = a2; ab2[1] = bs[0] - m2*a2;
        float m3 = stats2[2] / n, v3 = stats2[3] / n - m3*m3;
        float a3 = gt[0] * rsqrtf(v3 + 1e-5f);
        ab2[2] = a3; ab2[3] = bt[0] - m3*a3;
    }
}

// ---------- kernel 6: epilogue, float4 ----------
__global__ __launch_bounds__(256)
void k6_final(const float4* __restrict__ c2, const float4* __restrict__ c3,
              const float* __restrict__ ab2, float4* __restrict__ out) {
    int i = blockIdx.x * blockDim.x + threadIdx.x;
    if (i < NPER/4) {
        float a2 = ab2[0], b2 = ab2[1], a3 = ab2[2], b3 = ab2[3];
        float4 v2 = c2[i], v3 = c3[i];
        float4 sc, sh;
        sc.x = sigmoidf_(fmaf(a2, v2.x, b2) + 2.f) + 1e-4f;
        sc.y = sigmoidf_(fmaf(a2, v2.y, b2) + 2.f) + 1e-4f;
        sc.z = sigmoidf_(fmaf(a2, v2.z, b2) + 2.f) + 1e-4f;
        sc.w = sigmoidf_(fmaf(a2, v2.w, b2) + 2.f) + 1e-4f;
        sh.x = fmaf(a3, v3.x, b3);
        sh.y = fmaf(a3, v3.y, b3);
        sh.z = fmaf(a3, v3.z, b3);
        sh.w = fmaf(a3, v3.w, b3);
        out[i] = sc;
        out[NPER/4 + i] = sh;
    }
}

// ---------- launch ----------
extern "C" void kernel_launch(void* const* d_in, const int* in_sizes, int n_in,
                              void* d_out, int out_size, void* d_ws, size_t ws_size,
                              hipStream_t stream) {
    const float* in          = (const float*)d_in[0];
    const float* w_gate      = (const float*)d_in[1];
    const float* gamma_gate  = (const float*)d_in[2];
    const float* beta_gate   = (const float*)d_in[3];
    const float* w_scale     = (const float*)d_in[4];
    const float* gamma_scale = (const float*)d_in[5];
    const float* beta_scale  = (const float*)d_in[6];
    const float* w_shift     = (const float*)d_in[7];
    const float* gamma_shift = (const float*)d_in[8];
    const float* beta_shift  = (const float*)d_in[9];
    const int*   rev         = (const int*)d_in[10];

    unsigned short* g   = (unsigned short*)d_ws;                    // gates bf16 (z then f); z-half becomes h
    float* c2  = (float*)((char*)d_ws + C2_BYTE);                   // aliases dead f-gates
    float* c3  = c2 + NPER;
    float* st  = (float*)((char*)d_ws + STATS_BYTE);
    float* s1  = st;            // 64
    float* ab1 = st + 64;       // 64
    float* s2  = st + 128;      // 4
    float* ab2 = st + 132;      // 4
    float* out = (float*)d_out;

    hipMemsetAsync(st, 0, 136 * sizeof(float), stream);

    k1_gates_stats<<<dim3(8, 100, TB), 256, 0, stream>>>(in, w_gate, g, s1);
    k2_fin1<<<1, 32, 0, stream>>>(s1, gamma_gate, beta_gate, ab1);
    k3_scan<<<dim3(25, HCN, TB), 256, 0, stream>>>(g, ab1, rev);
    k4_conv23<<<dim3(100, 4, TB), 256, 0, stream>>>(g, w_scale, w_shift, c2, c3, s2);
    k5_fin2<<<1, 64, 0, stream>>>(s2, gamma_scale, beta_scale, gamma_shift, beta_shift, ab2);
    k6_final<<<(NPER/4 + 255)/256, 256, 0, stream>>>((const float4*)c2, (const float4*)c3, ab2, (float4*)out);
}

// Round 10
// 247.880 us; speedup vs baseline: 2.4941x; 1.0593x over previous
//
#include <hip/hip_runtime.h>
#include <math.h>

// Problem constants
#define TB 2
#define TT 31
#define TH 160
#define TW 160
#define THW (TH*TW)            // 25600
#define NPER (TB*TT*THW)       // 1,587,200
#define HCN 16
#define LSK 40                 // k1 LDS row stride

// Workspace layout (bytes). gates bf16: z-half [0,50.79MB), f-half [50.79,101.58MB).
// After k3, z-half is overwritten in-place with h (bf16). c2/c3 fp32 alias the
// (dead) f-half. Stats at the end. Total ~101.6MB.
#define GF_OFF_US  25395200L    // ushort offset of f-gates (2*16*31*25600)
#define C2_BYTE    50790400L    // byte offset of c2 (aliases f-gates, dead by then)
#define STATS_BYTE 101580800L

__device__ __forceinline__ float sigmoidf_(float x) {
    return __builtin_amdgcn_rcpf(1.f + __expf(-x));
}
__device__ __forceinline__ float tanhf_(float x) {
    return 2.f * __builtin_amdgcn_rcpf(1.f + __expf(-2.f * x)) - 1.f;
}
__device__ __forceinline__ unsigned short f2bf(float v) {
    unsigned int b = __float_as_uint(v);
    unsigned int r = (b + 0x7FFFu + ((b >> 16) & 1u)) >> 16;   // RNE
    return (unsigned short)r;
}
__device__ __forceinline__ float b2f(unsigned short u) {
    return __uint_as_float(((unsigned int)u) << 16);
}

// ---------- kernel 1: conv1 (all taps from LDS, no mid-loop barriers),
//            per-channel sum/sumsq + bf16 gate store ----------
// grid: (8 = chalf*4 + tchunk, 100 tiles, 2 b), block 256 = 32x8 tile
__global__ __launch_bounds__(256)
void k1_gates_stats(const float* __restrict__ in, const float* __restrict__ wg,
                    unsigned short* __restrict__ gout, float* __restrict__ stats) {
    __shared__ float pl[10*10*LSK];          // 10 t-planes, 10 rows x 40 (34 used)
    __shared__ float redS[4][16], redQ[4][16];

    int bx = blockIdx.x;
    int tc = bx & 3, chalf = bx >> 2;
    int tile = blockIdx.y, b = blockIdx.z;
    int ty0 = (tile / 5) * 8, tx0 = (tile % 5) * 32;
    int tid = threadIdx.x;
    int lyk = tid >> 5, lxk = tid & 31;
    int t0 = tc * 8;

    // stage 10 halo planes (t0-1 .. t0+8), 10x34 each, zero-padded
    for (int i = tid; i < 3400; i += 256) {
        int j = i / 340, pos = i - j*340;
        int py = pos / 34, px = pos - py*34;
        int t = t0 - 1 + j;
        int gy = ty0 - 1 + py, gx = tx0 - 1 + px;
        float v = 0.f;
        if (t >= 0 && t < TT && gy >= 0 && gy < TH && gx >= 0 && gx < TW)
            v = in[((long)(b*TT + t))*THW + gy*TW + gx];
        pl[j*(10*LSK) + py*LSK + px] = v;
    }
    __syncthreads();

    int c0 = chalf * 16;
    long gbase = chalf ? GF_OFF_US : 0L;
    int y = ty0 + lyk, x = tx0 + lxk;
    int hw = y*TW + x;

    float s[16], q[16];
    #pragma unroll
    for (int c = 0; c < 16; ++c) { s[c] = 0.f; q[c] = 0.f; }

    for (int j = 1; j <= 8; ++j) {
        int t = t0 - 1 + j;
        if (t >= TT) break;                  // uniform
        float tap[27];
        #pragma unroll
        for (int kt = 0; kt < 3; ++kt)
            #pragma unroll
            for (int ky = 0; ky < 3; ++ky)
                #pragma unroll
                for (int kx = 0; kx < 3; ++kx)
                    tap[kt*9 + ky*3 + kx] =
                        pl[(j-1+kt)*(10*LSK) + (lyk+ky)*LSK + (lxk+kx)];
        #pragma unroll
        for (int c = 0; c < 16; ++c) {
            const float* w = wg + (c0 + c)*27;
            float v = 0.f;
            #pragma unroll
            for (int i = 0; i < 27; ++i) v = fmaf(w[i], tap[i], v);
            s[c] += v; q[c] += v*v;
            gout[gbase + ((long)((b*HCN + c)*TT + t))*THW + hw] = f2bf(v);
        }
    }

    // block reduce 16 channels x (sum, sumsq)
    int lane = tid & 63, wid = tid >> 6;
    #pragma unroll
    for (int c = 0; c < 16; ++c) {
        float ss = s[c], qq = q[c];
        #pragma unroll
        for (int off = 32; off > 0; off >>= 1) {
            ss += __shfl_down(ss, off, 64);
            qq += __shfl_down(qq, off, 64);
        }
        if (lane == 0) { redS[wid][c] = ss; redQ[wid][c] = qq; }
    }
    __syncthreads();
    if (tid < 16) {
        int ch = c0 + tid;
        float ss = redS[0][tid] + redS[1][tid] + redS[2][tid] + redS[3][tid];
        float qq = redQ[0][tid] + redQ[1][tid] + redQ[2][tid] + redQ[3][tid];
        atomicAdd(&stats[ch], ss);
        atomicAdd(&stats[32 + ch], qq);
    }
}

// ---------- kernel 2: finalize gate BN params ----------
__global__ void k2_fin1(const float* __restrict__ stats, const float* __restrict__ gamma,
                        const float* __restrict__ beta, float* __restrict__ ab) {
    int c = threadIdx.x;
    if (c < 32) {
        float n = (float)NPER;
        float mean = stats[c] / n;
        float var  = stats[32 + c] / n - mean*mean;
        float a = gamma[c] * rsqrtf(var + 1e-5f);
        ab[c]      = a;
        ab[32 + c] = beta[c] - mean * a;
    }
}

// ---------- kernel 3: pointwise BN + act + scan (bf16 in, bf16 h in-place) ----------
// grid: (25, 16 ch, 2 b), block 256; each thread: 4 consecutive hw elems, scans t
__global__ __launch_bounds__(256)
void k3_scan(unsigned short* __restrict__ g, const float* __restrict__ ab,
             const int* __restrict__ rev_p) {
    int c = blockIdx.y, b = blockIdx.z;
    int p4 = blockIdx.x * blockDim.x + threadIdx.x;    // ushort4 index in plane
    float az = ab[c],      bz = ab[32 + c];
    float af = ab[16 + c], bf = ab[48 + c];
    int rev = rev_p[0];

    ushort4* g4 = (ushort4*)g;
    long zb = ((long)((b*HCN + c)*TT)) * (THW/4) + p4;
    long fb = zb + GF_OFF_US/4;

    float h0 = 0.f, h1 = 0.f, h2 = 0.f, h3 = 0.f;

#define K3_STEP(t)                                                        \
    {                                                                     \
        long o = (long)(t) * (THW/4);                                     \
        ushort4 zu = g4[zb + o];                                          \
        ushort4 fu = g4[fb + o];                                          \
        float z0 = tanhf_(fmaf(az, b2f(zu.x), bz));                       \
        float z1 = tanhf_(fmaf(az, b2f(zu.y), bz));                       \
        float z2 = tanhf_(fmaf(az, b2f(zu.z), bz));                       \
        float z3 = tanhf_(fmaf(az, b2f(zu.w), bz));                       \
        float f0 = sigmoidf_(fmaf(af, b2f(fu.x), bf));                    \
        float f1 = sigmoidf_(fmaf(af, b2f(fu.y), bf));                    \
        float f2 = sigmoidf_(fmaf(af, b2f(fu.z), bf));                    \
        float f3 = sigmoidf_(fmaf(af, b2f(fu.w), bf));                    \
        h0 = f0*h0 + (1.f - f0)*z0;                                       \
        h1 = f1*h1 + (1.f - f1)*z1;                                       \
        h2 = f2*h2 + (1.f - f2)*z2;                                       \
        h3 = f3*h3 + (1.f - f3)*z3;                                       \
        ushort4 hu;                                                       \
        hu.x = f2bf(h0); hu.y = f2bf(h1); hu.z = f2bf(h2); hu.w = f2bf(h3); \
        g4[zb + o] = hu;                                                  \
    }

    if (!rev) {
        for (int t = 0; t < TT; ++t) K3_STEP(t)
    } else {
        for (int t = TT - 1; t >= 0; --t) K3_STEP(t)
    }
#undef K3_STEP
}

// ---------- kernel 4: conv2+conv3 over bf16 h.
// LDS-issue-bound fix: 2 x-outputs per thread, bf16-PAIR-packed LDS (uint).
// Per plane: 6 packed LDS reads (one per conv x ky -> 4 taps for both outputs)
// + 108 FMA, vs 18 reads + 54 FMA before. Tile 32x16, block 256, LDS 5.8 KB.
// grid: (50 tiles, 8 t-chunks of 4, 2 b), block 256
#define K4TCH 4
__global__ __launch_bounds__(256)
void k4_conv23(const unsigned short* __restrict__ hb, const float* __restrict__ wsc,
               const float* __restrict__ wsh, float* __restrict__ c2,
               float* __restrict__ c3, float* __restrict__ stats2) {
    __shared__ unsigned int pl[2][2][18*20];   // [buf][conv][18 rows x 20 uints (17 used)]
    __shared__ float red[4][4];

    int b  = blockIdx.z;
    int t0 = blockIdx.y * K4TCH;
    int t1 = min(t0 + K4TCH - 1, TT - 1);
    int tile = blockIdx.x;
    int ty0 = (tile / 5) * 16, tx0 = (tile % 5) * 32;
    int tid = threadIdx.x;
    int k   = tid & 15;            // x-pair index
    int ly  = tid >> 4;            // row 0..15
    int y = ty0 + ly, x0 = tx0 + 2*k;

    int ts = max(t0 - 1, 0), te = min(t1 + 1, TT - 1);
    int nplanes = (te - ts + 1) * 8;   // <= 48

    // staging: 612 halo ushorts per conv-plane (18 rows x 34), 3 slots/thread
    int i0 = tid, i1 = tid + 256, i2 = tid + 512;
    int pyA = i0 / 34, pxA = i0 - pyA*34;
    int pyB = i1 / 34, pxB = i1 - pyB*34;
    int pyC = i2 / 34, pxC = i2 - pyC*34;
    int gyA = ty0 - 1 + pyA, gxA = tx0 - 1 + pxA;
    int gyB = ty0 - 1 + pyB, gxB = tx0 - 1 + pxB;
    int gyC = ty0 - 1 + pyC, gxC = tx0 - 1 + pxC;
    bool vB = (i1 < 612), vC = (i2 < 612);
    bool okA = (gyA >= 0 && gyA < TH && gxA >= 0 && gxA < TW);
    bool okB = vB && (gyB >= 0 && gyB < TH && gxB >= 0 && gxB < TW);
    bool okC = vC && (gyC >= 0 && gyC < TH && gxC >= 0 && gxC < TW);
    long offA = (long)gyA*TW + gxA, offB = (long)gyB*TW + gxB, offC = (long)gyC*TW + gxC;
    int lA = pyA*40 + pxA, lB = pyB*40 + pxB, lC = pyC*40 + pxC;  // ushort idx, stride 40

    // rolling accumulators: 2 outputs x 3 temporal x 2 convs
    float aP2x=0.f,aP2y=0.f,aC2x=0.f,aC2y=0.f,aN2x=0.f,aN2y=0.f;
    float aP3x=0.f,aP3y=0.f,aC3x=0.f,aC3y=0.f,aN3x=0.f,aN3y=0.f;
    float s2l = 0.f, q2l = 0.f, s3l = 0.f, q3l = 0.f;

    // prefetch plane 0
    unsigned short r2A, r2B, r2C, r3A, r3B, r3C;
    {
        long b2o = ((long)((b*HCN + 0)*TT + ts)) * THW;
        long b3o = ((long)((b*HCN + 8)*TT + ts)) * THW;
        r2A = okA ? hb[b2o + offA] : 0;
        r2B = okB ? hb[b2o + offB] : 0;
        r2C = okC ? hb[b2o + offC] : 0;
        r3A = okA ? hb[b3o + offA] : 0;
        r3B = okB ? hb[b3o + offB] : 0;
        r3C = okC ? hb[b3o + offC] : 0;
    }

    for (int p = 0; p < nplanes; ++p) {
        int buf = p & 1;
        int c = p & 7, t_in = ts + (p >> 3);

        unsigned short* p2 = (unsigned short*)&pl[buf][0][0];
        unsigned short* p3 = (unsigned short*)&pl[buf][1][0];
        p2[lA] = r2A;  p3[lA] = r3A;
        if (vB) { p2[lB] = r2B; p3[lB] = r3B; }
        if (vC) { p2[lC] = r2C; p3[lC] = r3C; }

        if (p + 1 < nplanes) {
            int cn = (p + 1) & 7, tn = ts + ((p + 1) >> 3);
            long b2o = ((long)((b*HCN + cn)*TT + tn)) * THW;
            long b3o = ((long)((b*HCN + 8 + cn)*TT + tn)) * THW;
            r2A = okA ? hb[b2o + offA] : 0;
            r2B = okB ? hb[b2o + offB] : 0;
            r2C = okC ? hb[b2o + offC] : 0;
            r3A = okA ? hb[b3o + offA] : 0;
            r3B = okB ? hb[b3o + offB] : 0;
            r3C = okC ? hb[b3o + offC] : 0;
        }
        __syncthreads();

        const float* w2 = wsc + c*27;
        const float* w3 = wsh + c*27;
        #pragma unroll
        for (int ky = 0; ky < 3; ++ky) {
            int ub = (ly + ky)*20 + k;
            // conv2
            {
                unsigned int u0 = pl[buf][0][ub], u1 = pl[buf][0][ub + 1];
                float v0 = __uint_as_float(u0 << 16);
                float v1 = __uint_as_float(u0 & 0xffff0000u);
                float v2 = __uint_as_float(u1 << 16);
                float v3 = __uint_as_float(u1 & 0xffff0000u);
                float wN0 = w2[ky*3+0],   wN1 = w2[ky*3+1],   wN2 = w2[ky*3+2];
                float wC0 = w2[9+ky*3+0], wC1 = w2[9+ky*3+1], wC2 = w2[9+ky*3+2];
                float wP0 = w2[18+ky*3+0],wP1 = w2[18+ky*3+1],wP2 = w2[18+ky*3+2];
                aN2x = fmaf(wN0,v0,aN2x); aN2x = fmaf(wN1,v1,aN2x); aN2x = fmaf(wN2,v2,aN2x);
                aN2y = fmaf(wN0,v1,aN2y); aN2y = fmaf(wN1,v2,aN2y); aN2y = fmaf(wN2,v3,aN2y);
                aC2x = fmaf(wC0,v0,aC2x); aC2x = fmaf(wC1,v1,aC2x); aC2x = fmaf(wC2,v2,aC2x);
                aC2y = fmaf(wC0,v1,aC2y); aC2y = fmaf(wC1,v2,aC2y); aC2y = fmaf(wC2,v3,aC2y);
                aP2x = fmaf(wP0,v0,aP2x); aP2x = fmaf(wP1,v1,aP2x); aP2x = fmaf(wP2,v2,aP2x);
                aP2y = fmaf(wP0,v1,aP2y); aP2y = fmaf(wP1,v2,aP2y); aP2y = fmaf(wP2,v3,aP2y);
            }
            // conv3
            {
                unsigned int u0 = pl[buf][1][ub], u1 = pl[buf][1][ub + 1];
                float v0 = __uint_as_float(u0 << 16);
                float v1 = __uint_as_float(u0 & 0xffff0000u);
                float v2 = __uint_as_float(u1 << 16);
                float v3 = __uint_as_float(u1 & 0xffff0000u);
                float wN0 = w3[ky*3+0],   wN1 = w3[ky*3+1],   wN2 = w3[ky*3+2];
                float wC0 = w3[9+ky*3+0], wC1 = w3[9+ky*3+1], wC2 = w3[9+ky*3+2];
                float wP0 = w3[18+ky*3+0],wP1 = w3[18+ky*3+1],wP2 = w3[18+ky*3+2];
                aN3x = fmaf(wN0,v0,aN3x); aN3x = fmaf(wN1,v1,aN3x); aN3x = fmaf(wN2,v2,aN3x);
                aN3y = fmaf(wN0,v1,aN3y); aN3y = fmaf(wN1,v2,aN3y); aN3y = fmaf(wN2,v3,aN3y);
                aC3x = fmaf(wC0,v0,aC3x); aC3x = fmaf(wC1,v1,aC3x); aC3x = fmaf(wC2,v2,aC3x);
                aC3y = fmaf(wC0,v1,aC3y); aC3y = fmaf(wC1,v2,aC3y); aC3y = fmaf(wC2,v3,aC3y);
                aP3x = fmaf(wP0,v0,aP3x); aP3x = fmaf(wP1,v1,aP3x); aP3x = fmaf(wP2,v2,aP3x);
                aP3y = fmaf(wP0,v1,aP3y); aP3y = fmaf(wP1,v2,aP3y); aP3y = fmaf(wP2,v3,aP3y);
            }
        }

        if (c == 7) {
            int t_out = t_in - 1;
            if (t_out >= t0 && t_out <= t1) {
                long oidx = ((long)(b*TT + t_out)) * THW + (long)y*TW + x0;
                *(float2*)&c2[oidx] = make_float2(aP2x, aP2y);
                *(float2*)&c3[oidx] = make_float2(aP3x, aP3y);
                s2l += aP2x + aP2y; q2l += aP2x*aP2x + aP2y*aP2y;
                s3l += aP3x + aP3y; q3l += aP3x*aP3x + aP3y*aP3y;
            }
            aP2x=aC2x; aC2x=aN2x; aN2x=0.f;  aP2y=aC2y; aC2y=aN2y; aN2y=0.f;
            aP3x=aC3x; aC3x=aN3x; aN3x=0.f;  aP3y=aC3y; aC3y=aN3y; aN3y=0.f;
        }
    }
    if (t1 == TT - 1) {
        long oidx = ((long)(b*TT + (TT - 1))) * THW + (long)y*TW + x0;
        *(float2*)&c2[oidx] = make_float2(aP2x, aP2y);
        *(float2*)&c3[oidx] = make_float2(aP3x, aP3y);
        s2l += aP2x + aP2y; q2l += aP2x*aP2x + aP2y*aP2y;
        s3l += aP3x + aP3y; q3l += aP3x*aP3x + aP3y*aP3y;
    }

    #pragma unroll
    for (int off = 32; off > 0; off >>= 1) {
        s2l += __shfl_down(s2l, off, 64);
        q2l += __shfl_down(q2l, off, 64);
        s3l += __shfl_down(s3l, off, 64);
        q3l += __shfl_down(q3l, off, 64);
    }
    int lane = tid & 63, wid = tid >> 6;
    __syncthreads();
    if (lane == 0) { red[0][wid] = s2l; red[1][wid] = q2l; red[2][wid] = s3l; red[3][wid] = q3l; }
    __syncthreads();
    if (tid == 0) {
        #pragma unroll
        for (int j = 0; j < 4; ++j)
            atomicAdd(&stats2[j], red[j][0] + red[j][1] + red[j][2] + red[j][3]);
    }
}

// ---------- kernel 5: finalize scale/shift BN params ----------
__global__ void k5_fin2(const float* __restrict__ stats2,
                        const float* __restrict__ gs, const float* __restrict__ bs,
                        const float* __restrict__ gt, const float* __restrict__ bt,
                        float* __restrict__ ab2) {
    if (threadIdx.x == 0) {
        float n = (float)NPER;
        float m2 = stats2[0] / n, v2 = stats2[1] / n - m2*m2;
        float a2 = gs[0] * rsqrtf(v2 + 1e-5f);
        ab2[0] = a2; ab2[1] = bs[0] - m2*a2;
        float m3 = stats2[2] / n, v3 = stats2[3] / n - m3*m3;
        float a3 = gt[0] * rsqrtf(v3 + 1e-5f);
        ab2[2] = a3; ab2[3] = bt[0] - m3*a3;
    }
}

// ---------- kernel 6: epilogue, float4 ----------
__global__ __launch_bounds__(256)
void k6_final(const float4* __restrict__ c2, const float4* __restrict__ c3,
              const float* __restrict__ ab2, float4* __restrict__ out) {
    int i = blockIdx.x * blockDim.x + threadIdx.x;
    if (i < NPER/4) {
        float a2 = ab2[0], b2 = ab2[1], a3 = ab2[2], b3 = ab2[3];
        float4 v2 = c2[i], v3 = c3[i];
        float4 sc, sh;
        sc.x = sigmoidf_(fmaf(a2, v2.x, b2) + 2.f) + 1e-4f;
        sc.y = sigmoidf_(fmaf(a2, v2.y, b2) + 2.f) + 1e-4f;
        sc.z = sigmoidf_(fmaf(a2, v2.z, b2) + 2.f) + 1e-4f;
        sc.w = sigmoidf_(fmaf(a2, v2.w, b2) + 2.f) + 1e-4f;
        sh.x = fmaf(a3, v3.x, b3);
        sh.y = fmaf(a3, v3.y, b3);
        sh.z = fmaf(a3, v3.z, b3);
        sh.w = fmaf(a3, v3.w, b3);
        out[i] = sc;
        out[NPER/4 + i] = sh;
    }
}

// ---------- launch ----------
extern "C" void kernel_launch(void* const* d_in, const int* in_sizes, int n_in,
                              void* d_out, int out_size, void* d_ws, size_t ws_size,
                              hipStream_t stream) {
    const float* in          = (const float*)d_in[0];
    const float* w_gate      = (const float*)d_in[1];
    const float* gamma_gate  = (const float*)d_in[2];
    const float* beta_gate   = (const float*)d_in[3];
    const float* w_scale     = (const float*)d_in[4];
    const float* gamma_scale = (const float*)d_in[5];
    const float* beta_scale  = (const float*)d_in[6];
    const float* w_shift     = (const float*)d_in[7];
    const float* gamma_shift = (const float*)d_in[8];
    const float* beta_shift  = (const float*)d_in[9];
    const int*   rev         = (const int*)d_in[10];

    unsigned short* g   = (unsigned short*)d_ws;                    // gates bf16 (z then f); z-half becomes h
    float* c2  = (float*)((char*)d_ws + C2_BYTE);                   // aliases dead f-gates
    float* c3  = c2 + NPER;
    float* st  = (float*)((char*)d_ws + STATS_BYTE);
    float* s1  = st;            // 64
    float* ab1 = st + 64;       // 64
    float* s2  = st + 128;      // 4
    float* ab2 = st + 132;      // 4
    float* out = (float*)d_out;

    hipMemsetAsync(st, 0, 136 * sizeof(float), stream);

    k1_gates_stats<<<dim3(8, 100, TB), 256, 0, stream>>>(in, w_gate, g, s1);
    k2_fin1<<<1, 32, 0, stream>>>(s1, gamma_gate, beta_gate, ab1);
    k3_scan<<<dim3(25, HCN, TB), 256, 0, stream>>>(g, ab1, rev);
    k4_conv23<<<dim3(50, 8, TB), 256, 0, stream>>>(g, w_scale, w_shift, c2, c3, s2);
    k5_fin2<<<1, 64, 0, stream>>>(s2, gamma_scale, beta_scale, gamma_shift, beta_shift, ab2);
    k6_final<<<(NPER/4 + 255)/256, 256, 0, stream>>>((const float4*)c2, (const float4*)c3, ab2, (float4*)out);
}